// Round 7
// baseline (67.418 us; speedup 1.0000x reference)
//
#include <hip/hip_runtime.h>

// RaySamplerPDF: per-ray inverse-CDF sampling (NeRF fine sampling).
// 2 rays per wave (one per 32-lane half); lane sl owns bins 4sl..4sl+3
// (float4 load, DPP segmented scan) and samples {sl, sl+32, sl+64, sl+96}.
//
// DS-pipe minimization:
//  - CDF stored BIT-REVERSED in LDS: slot sigma(j)=rev7(j) holds cdf[j+1].
//    Tree descent level with step s reads addr = sa + sigma(s-1) (disjoint
//    bits -> OR==ADD, folds into ds_read offset imm); candidate sets are
//    contiguous sigma-windows -> bank-conflict-free at every level.
//  - Top 3 descent levels use scalars (cdf[16k] via v_readlane + cndmask
//    by half) -> only 4 LDS reads per sample.
//  - Bracket (cb,ca) tracked during descent (2 cndmask/level) -> the final
//    lerp needs NO epilogue LDS gather; ca init = cdf[128] via readlane.

typedef float f32x4 __attribute__((ext_vector_type(4)));

constexpr int NUM_BINS = 128;
constexpr float EPS_PAD = 1e-5f;
constexpr float INV_S   = 1.0f / 128.0f;
constexpr int RPB       = 8;    // rays per 256-thread block (2 per wave)

template <int CTRL, int ROW_MASK>
__device__ __forceinline__ float dpp_add(float x) {
    int s = __builtin_amdgcn_update_dpp(0, __float_as_int(x), CTRL, ROW_MASK, 0xf, true);
    return x + __int_as_float(s);
}

__device__ __forceinline__ float rl(float v, int lane) {
    return __int_as_float(__builtin_amdgcn_readlane(__float_as_int(v), lane));
}

__global__ __launch_bounds__(256) void ray_sampler_kernel(
    const float* __restrict__ W,
    const float* __restrict__ U,
    const int*   __restrict__ stratp,
    float*       __restrict__ out)
{
    const int wave = threadIdx.x >> 6;
    const int lane = threadIdx.x & 63;
    const int h    = lane >> 5;          // ray within wave
    const int sl   = lane & 31;          // lane within 32-lane segment
    const int ray  = blockIdx.x * RPB + wave * 2 + h;

    __shared__ float cdf_s[RPB][NUM_BINS];   // sigma-ordered, 128 slots/ray
    float* cw = cdf_s[wave * 2 + h];

    const size_t rb = (size_t)ray * NUM_BINS;
    const int strat = *stratp;

    // ---- sample uniforms (stride-1 across lanes) ----
    const float ur0 = U[rb + sl];
    const float ur1 = U[rb + sl + 32];
    const float ur2 = U[rb + sl + 64];
    const float ur3 = U[rb + sl + 96];

    // ---- weights: contiguous quad per lane ----
    const int b = 4 * sl;
    const f32x4 w4 = *reinterpret_cast<const f32x4*>(W + rb + b);
    const float s1 = w4.x;
    const float s2 = s1 + w4.y;
    const float s3 = s2 + w4.z;
    const float quad = s3 + w4.w;

    // 32-lane segmented inclusive scan of quad sums (DPP, no LDS)
    float incl = quad;
    incl = dpp_add<0x111, 0xf>(incl);   // row_shr:1
    incl = dpp_add<0x112, 0xf>(incl);   // row_shr:2
    incl = dpp_add<0x114, 0xf>(incl);   // row_shr:4
    incl = dpp_add<0x118, 0xf>(incl);   // row_shr:8
    incl = dpp_add<0x142, 0xa>(incl);   // row_bcast:15 (32-lane segments)

    const float totA = rl(incl, 31), totB = rl(incl, 63);
    const float tot  = h ? totB : totA;
    const float padding = fmaxf(EPS_PAD - tot, 0.0f);
    const float ppb     = padding * INV_S;
    const float inv     = __builtin_amdgcn_rcpf(tot + padding);
    const float pre     = incl - quad;

    f32x4 st;                                  // in-order slots b..b+3 = cdf[b+1..b+4]
    st.x = (pre + s1   + (float)(b + 1) * ppb) * inv;
    st.y = (pre + s2   + (float)(b + 2) * ppb) * inv;
    st.z = (pre + s3   + (float)(b + 3) * ppb) * inv;
    st.w = (pre + quad + (float)(b + 4) * ppb) * inv;

    // bit-reversed writes: sigma(4sl+c) = 64*(c&1) + 32*(c>>1) + rev5(sl)
    const int r5 = (int)(__brev((unsigned)sl) >> 27);
    cw[r5]      = st.x;   // c=0
    cw[r5 + 64] = st.y;   // c=1
    cw[r5 + 32] = st.z;   // c=2
    cw[r5 + 96] = st.w;   // c=3

    // scalar top-level values: cdf[16k] = st.w of lane (4k-1) per half; cdf[128] = lane31.w
    const float v16  = h ? rl(st.w, 35) : rl(st.w, 3);
    const float v32  = h ? rl(st.w, 39) : rl(st.w, 7);
    const float v48  = h ? rl(st.w, 43) : rl(st.w, 11);
    const float v64  = h ? rl(st.w, 47) : rl(st.w, 15);
    const float v80  = h ? rl(st.w, 51) : rl(st.w, 19);
    const float v96  = h ? rl(st.w, 55) : rl(st.w, 23);
    const float v112 = h ? rl(st.w, 59) : rl(st.w, 27);
    const float v128 = h ? rl(st.w, 63) : rl(st.w, 31);

    // drain LDS writes (wave-private slice -> no block barrier needed)
    asm volatile("s_waitcnt lgkmcnt(0)" ::: "memory");

    const float uu0 = strat ? ur0 : 0.5f;
    const float uu1 = strat ? ur1 : 0.5f;
    const float uu2 = strat ? ur2 : 0.5f;
    const float uu3 = strat ? ur3 : 0.5f;
    const float us0 = ((float)(sl)      + uu0) * INV_S;
    const float us1 = ((float)(sl + 32) + uu1) * INV_S;
    const float us2 = ((float)(sl + 64) + uu2) * INV_S;
    const float us3 = ((float)(sl + 96) + uu3) * INV_S;

    auto search = [&](float us) -> float {
        // top 3 levels from scalars; maintain bracket cb=cdf[a], ca=cdf[upper]
        const bool p0 = (v64 <= us);
        float cb = p0 ? v64 : 0.0f;
        float ca = p0 ? v128 : v64;
        int sa = p0 ? 1 : 0;

        const float m1 = p0 ? v96 : v32;
        const bool p1 = (m1 <= us);
        cb = p1 ? m1 : cb;  ca = p1 ? ca : m1;  sa += p1 ? 2 : 0;

        const float m2h = p0 ? v112 : v48;
        const float m2l = p0 ? v80  : v16;
        const float m2  = p1 ? m2h : m2l;
        const bool p2 = (m2 <= us);
        cb = p2 ? m2 : cb;  ca = p2 ? ca : m2;  sa += p2 ? 4 : 0;

        // LDS levels (sigma-space): addr = sa + sigma(step-1), delta = sigma(step)
        {   const float v = cw[sa + 112];                 // step 8
            const bool p = (v <= us);
            cb = p ? v : cb;  ca = p ? ca : v;  sa += p ? 8 : 0;  }
        {   const float v = cw[sa + 96];                  // step 4
            const bool p = (v <= us);
            cb = p ? v : cb;  ca = p ? ca : v;  sa += p ? 16 : 0; }
        {   const float v = cw[sa + 64];                  // step 2
            const bool p = (v <= us);
            cb = p ? v : cb;  ca = p ? ca : v;  sa += p ? 32 : 0; }
        {   const float v = cw[sa];                       // step 1
            const bool p = (v <= us);
            cb = p ? v : cb;  ca = p ? ca : v;  sa += p ? 64 : 0; }

        const int a = (int)(__brev((unsigned)sa) >> 25);  // rev7(sa)
        float d = ca - cb;
        d = (d < 1e-5f) ? 1.0f : d;
        const float t = (us - cb) * __builtin_amdgcn_rcpf(d);
        return ((float)a + t) * INV_S;
    };

    const float o0 = search(us0);
    const float o1 = search(us1);
    const float o2 = search(us2);
    const float o3 = search(us3);

    __builtin_nontemporal_store(o0, out + rb + sl);
    __builtin_nontemporal_store(o1, out + rb + sl + 32);
    __builtin_nontemporal_store(o2, out + rb + sl + 64);
    __builtin_nontemporal_store(o3, out + rb + sl + 96);
}

extern "C" void kernel_launch(void* const* d_in, const int* in_sizes, int n_in,
                              void* d_out, int out_size, void* d_ws, size_t ws_size,
                              hipStream_t stream) {
    const float* W     = (const float*)d_in[0];
    const float* U     = (const float*)d_in[1];
    const int*   strat = (const int*)d_in[2];
    float*       out   = (float*)d_out;

    const int num_rays = in_sizes[0] / NUM_BINS;   // 262144
    const int blocks   = num_rays / RPB;           // 32768
    hipLaunchKernelGGL(ray_sampler_kernel, dim3(blocks), dim3(256), 0, stream,
                       W, U, strat, out);
}

// Round 8
// 64.970 us; speedup vs baseline: 1.0377x; 1.0377x over previous
//
#include <hip/hip_runtime.h>

// RaySamplerPDF: per-ray inverse-CDF sampling (NeRF fine sampling).
// 4 rays per wave (one per 16-lane group); lane g,sl owns:
//   bins  {4sl..4sl+3} and {64+4sl..64+4sl+3} (two float4 quads)
//   samples {16c+sl : c=0..7}  (strided -> bank-spread search, monotone ILP)
// CDF via two 16-lane DPP scans (row_shr only; rows == 16 lanes); LDS slot
// j = cdf[j+1], slice stride 136 floats (8 mod 32 -> search reads 2/bank).
// R6-proven branchless descent (cmp + cndmask-add per level), epilogue
// cb/ca via ds_read2_b32. 8 independent chains/lane hide LDS latency.

typedef float f32x4 __attribute__((ext_vector_type(4)));

constexpr int NUM_BINS = 128;
constexpr float EPS_PAD = 1e-5f;
constexpr float INV_S   = 1.0f / 128.0f;
constexpr int RPB       = 16;    // rays per 256-thread block (4 per wave)
constexpr int STRIDE    = 136;   // LDS slice stride (floats)

template <int CTRL, int ROW_MASK>
__device__ __forceinline__ float dpp_add(float x) {
    int s = __builtin_amdgcn_update_dpp(0, __float_as_int(x), CTRL, ROW_MASK, 0xf, true);
    return x + __int_as_float(s);
}

__global__ __launch_bounds__(256) void ray_sampler_kernel(
    const float* __restrict__ W,
    const float* __restrict__ U,
    const int*   __restrict__ stratp,
    float*       __restrict__ out)
{
    const int wave = threadIdx.x >> 6;
    const int lane = threadIdx.x & 63;
    const int g    = lane >> 4;          // ray within wave
    const int sl   = lane & 15;          // lane within 16-lane group
    const int ray  = blockIdx.x * RPB + wave * 4 + g;

    __shared__ float cdf_s[RPB][STRIDE];
    float* cw = cdf_s[wave * 4 + g];

    const size_t rb = (size_t)ray * NUM_BINS;
    const int strat = *stratp;

    // ---- issue all global loads up front (MLP) ----
    const f32x4 qA = *reinterpret_cast<const f32x4*>(W + rb + 4 * sl);
    const f32x4 qB = *reinterpret_cast<const f32x4*>(W + rb + 64 + 4 * sl);
    float ur[8];
    #pragma unroll
    for (int c = 0; c < 8; ++c) ur[c] = U[rb + 16 * c + sl];

    // ---- in-lane prefixes of the two quads ----
    const float a1 = qA.x, a2 = a1 + qA.y, a3 = a2 + qA.z, a4 = a3 + qA.w;
    const float b1 = qB.x, b2 = b1 + qB.y, b3 = b2 + qB.z, b4 = b3 + qB.w;

    // ---- 16-lane inclusive scans (DPP row_shr; rows are exactly 16 lanes) ----
    float iA = a4, iB = b4;
    iA = dpp_add<0x111, 0xf>(iA);  iB = dpp_add<0x111, 0xf>(iB);   // shr 1
    iA = dpp_add<0x112, 0xf>(iA);  iB = dpp_add<0x112, 0xf>(iB);   // shr 2
    iA = dpp_add<0x114, 0xf>(iA);  iB = dpp_add<0x114, 0xf>(iB);   // shr 4
    iA = dpp_add<0x118, 0xf>(iA);  iB = dpp_add<0x118, 0xf>(iB);   // shr 8

    // group totals (lane g*16+15) via bpermute
    const float totA = __shfl(iA, lane | 15, 64);
    const float totB = __shfl(iB, lane | 15, 64);
    const float tot  = totA + totB;

    const float padding = fmaxf(EPS_PAD - tot, 0.0f);
    const float ppb     = padding * INV_S;
    const float inv     = __builtin_amdgcn_rcpf(tot + padding);
    const float preA    = iA - a4;
    const float preB    = iB - b4;

    // ---- CDF slots: j = cdf[j+1]; A half at 4sl, B half at 64+4sl ----
    const int bA = 4 * sl, bB = 64 + 4 * sl;
    f32x4 stA, stB;
    stA.x = (preA + a1 + (float)(bA + 1) * ppb) * inv;
    stA.y = (preA + a2 + (float)(bA + 2) * ppb) * inv;
    stA.z = (preA + a3 + (float)(bA + 3) * ppb) * inv;
    stA.w = (preA + a4 + (float)(bA + 4) * ppb) * inv;
    stB.x = (totA + preB + b1 + (float)(bB + 1) * ppb) * inv;
    stB.y = (totA + preB + b2 + (float)(bB + 2) * ppb) * inv;
    stB.z = (totA + preB + b3 + (float)(bB + 3) * ppb) * inv;
    stB.w = (totA + preB + b4 + (float)(bB + 4) * ppb) * inv;
    *reinterpret_cast<f32x4*>(cw + bA) = stA;
    *reinterpret_cast<f32x4*>(cw + bB) = stB;

    // wave-private producer->consumer: drain LDS ops, no block barrier needed
    asm volatile("s_waitcnt lgkmcnt(0)" ::: "memory");

    // ---- 8 samples: us_c = (16c + sl + uu)/128 ----
    float us[8];
    #pragma unroll
    for (int c = 0; c < 8; ++c) {
        const float uu = strat ? ur[c] : 0.5f;
        us[c] = ((float)(16 * c + sl) + uu) * INV_S;
    }

    // ---- branchless bit-descent, 8 independent chains ----
    int av[8];
    #pragma unroll
    for (int c = 0; c < 8; ++c) av[c] = 0;
    #pragma unroll
    for (int step = 64; step; step >>= 1) {
        #pragma unroll
        for (int c = 0; c < 8; ++c) {
            const float v = cw[av[c] + (step - 1)];
            if (v <= us[c]) av[c] += step;
        }
    }

    // ---- epilogue: cb = cdf[a] (slot a-1 | 0), ca = cdf[a+1] (slot a) ----
    #pragma unroll
    for (int c = 0; c < 8; ++c) {
        const int a = av[c];
        const int m = a ? a - 1 : 0;
        const float lo = cw[m], hi = cw[m + 1];      // ds_read2_b32
        const float cb = a ? lo : 0.0f;
        const float ca = a ? hi : lo;
        float d = ca - cb;
        d = (d < 1e-5f) ? 1.0f : d;
        const float t = (us[c] - cb) * __builtin_amdgcn_rcpf(d);
        const float o = ((float)a + t) * INV_S;
        __builtin_nontemporal_store(o, out + rb + 16 * c + sl);
    }
}

extern "C" void kernel_launch(void* const* d_in, const int* in_sizes, int n_in,
                              void* d_out, int out_size, void* d_ws, size_t ws_size,
                              hipStream_t stream) {
    const float* W     = (const float*)d_in[0];
    const float* U     = (const float*)d_in[1];
    const int*   strat = (const int*)d_in[2];
    float*       out   = (float*)d_out;

    const int num_rays = in_sizes[0] / NUM_BINS;   // 262144
    const int blocks   = num_rays / RPB;           // 16384
    hipLaunchKernelGGL(ray_sampler_kernel, dim3(blocks), dim3(256), 0, stream,
                       W, U, strat, out);
}